// Round 5
// baseline (2153.506 us; speedup 1.0000x reference)
//
#include <hip/hip_runtime.h>
#include <hip/hip_fp16.h>

#define T_LEN 192

typedef unsigned long long u64;
typedef _Float16 f16x8 __attribute__((ext_vector_type(8)));
typedef float f32x4 __attribute__((ext_vector_type(4)));

// ws float offsets
#define OFF_X1F   0          // X1F [192][64 tile][16 b][16 row] f32
#define OFF_XPRE  3145728    // [192][16][1024]
#define OFF_XB3   6291456    // x@Ws3 + Ws_b  [192][16][256]
#define OFF_HSB   7077888    // hsB [16][192][256]
#define OFF_HX    7864320    // u64 [2][256][16]   lstm h exchange
#define OFF_HB    7880704    // u64 [16][256]      task h
#define OFF_HP    7888896    // u64 [16][8][256]   task hterm partials
#define OFF_E     7954432    // u64 [16][192]      task scores (exp'd)
#define OFF_CN    7960576    // u32 [192]          X1 ready counters
#define INIT_WORDS 96448

// ---- task LDS byte offsets ----
#define L_WCH   0        // u32[128][132]
#define L_G     67584    // u32[128][100]
#define L_WS2   118784   // u32[256][17]
#define L_BASES 136192   // u32[24][129]
#define L_HT2   148576   // f32[512]
#define L_H2L   150624   // u32[128]
#define L_EL    151136   // f32[192]
#define L_EH2   151904   // u32[96]
#define L_PREL  152288   // f32[128]
#define L_HN2   152800   // u32[16]
#define L_MSC   152864   // f32[8]
#define L_HL    152896   // f32[256]
#define L_XPL   153920   // f32[128]
#define L_HNL   154432   // f32[32]
#define L_USL   154560   // f32[256]
// prologue aliases
#define L_HSL   0        // u32[192][128]
#define L_CHUNK 118784   // u32[32][128]
#define L_BF32  136192   // f32[24][257]
#define SMEM_TASK 160864

__device__ __forceinline__ unsigned packh2(float a, float b){
  union { __half2 h; unsigned u; } v;
  v.h = __halves2half2(__float2half(a), __float2half(b));
  return v.u;
}
__device__ __forceinline__ float2 unp2(unsigned u){
  union { unsigned u32; __half2 h; } v; v.u32 = u;
  return __half22float2(v.h);
}
__device__ __forceinline__ float fdot2(unsigned a, unsigned b, float c){
#if __has_builtin(__builtin_amdgcn_fdot2)
  typedef _Float16 h2t __attribute__((ext_vector_type(2)));
  union { unsigned u; h2t h; } ua, ub;
  ua.u = a; ub.u = b;
  return __builtin_amdgcn_fdot2(ua.h, ub.h, c, false);
#else
  float2 x = unp2(a), y = unp2(b);
  return c + x.x*y.x + x.y*y.y;
#endif
}
__device__ __forceinline__ float tanh_f(float x){
  float cx = fminf(fmaxf(x, -15.f), 15.f);
  float e = __expf(2.f * cx);
  return (e - 1.f) / (e + 1.f);
}
__device__ __forceinline__ float sigm(float x){
  float cx = fminf(fmaxf(x, -30.f), 30.f);
  return 1.f / (1.f + __expf(-cx));
}
__device__ __forceinline__ u64 gld64(const u64* p){
  return __hip_atomic_load(p, __ATOMIC_RELAXED, __HIP_MEMORY_SCOPE_AGENT);
}
__device__ __forceinline__ void gst64(u64* p, u64 v){
  __hip_atomic_store(p, v, __ATOMIC_RELAXED, __HIP_MEMORY_SCOPE_AGENT);
}
__device__ __forceinline__ unsigned gldu(const unsigned* p){
  return __hip_atomic_load(p, __ATOMIC_RELAXED, __HIP_MEMORY_SCOPE_AGENT);
}
__device__ __forceinline__ void gstf(float* p, float v){
  __hip_atomic_store(p, v, __ATOMIC_RELAXED, __HIP_MEMORY_SCOPE_AGENT);
}
__device__ __forceinline__ u64 mk64(float f, unsigned tag){
  return ((u64)__float_as_uint(f) << 32) | (u64)tag;
}
__device__ __forceinline__ float pay(u64 v){ return __uint_as_float((unsigned)(v >> 32)); }

__global__ __launch_bounds__(256) void initk(float* p, int n){
  int i = blockIdx.x * blockDim.x + threadIdx.x;
  int stride = gridDim.x * blockDim.x;
  for (; i < n; i += stride) p[i] = 0.f;
}

// ===================== fused: proj (1728 WGs) + lstm (bids 0,8 -> same XCD) ==
__global__ __launch_bounds__(512, 2) void fused_pl(
    const float* __restrict__ x, const float* __restrict__ W_ih,
    const float* __restrict__ b_l, const float* __restrict__ Wc,
    const float* __restrict__ bc, const float* __restrict__ Ws_w,
    const float* __restrict__ Ws_b, const float* __restrict__ W_hh,
    float* __restrict__ ws){
  __shared__ float smem[12832];   // 51328 B: proj As+Wsh / lstm hT
  const int tid = threadIdx.x;
  const int bid = blockIdx.x;

  if (bid == 0 || bid == 8) {
    // ------------- LSTM: 2 WGs x 512 thr, W_hh in VGPRs via MFMA -------------
    unsigned* hT = (unsigned*)smem;         // [16 b][136] u32 (f16 pairs of h)
    const u64* X1 = (const u64*)(ws + OFF_X1F);
    u64* hx = (u64*)(ws + OFF_HX);
    const unsigned* cnt = (const unsigned*)(ws + OFF_CN);
    float* hsB = ws + OFF_HSB;
    const int wg = (bid == 8) ? 1 : 0;
    const int wave = tid >> 6, lane = tid & 63;
    const int b16 = lane & 15, quad = lane >> 4;
    const int jb = wg * 8 + wave;
    const int peer0 = (1 - wg) * 128;

    f16x8 wf[4][8];
    #pragma unroll
    for (int g = 0; g < 4; ++g) {
      #pragma unroll
      for (int kk = 0; kk < 8; ++kk) {
        int row = g * 256 + jb * 16 + b16;
        const float* wp = &W_hh[row * 256 + kk * 32 + quad * 8];
        f16x8 v;
        #pragma unroll
        for (int j = 0; j < 8; ++j) v[j] = (_Float16)wp[j];
        wf[g][kk] = v;
      }
    }
    for (int i = tid; i < 16 * 136; i += 512) hT[i] = 0u;
    float cst[4] = {0.f, 0.f, 0.f, 0.f};
    __syncthreads();

    for (int t = 0; t < T_LEN; ++t) {
      // wait for X1(t) from proj WGs, then load (atomic: bypass stale L2)
      while (gldu(&cnt[t]) < 32u) {}
      float4 xi[4];
      #pragma unroll
      for (int g = 0; g < 4; ++g) {
        u64 base = (u64)(((t * 64 + g * 16 + jb) * 16 + b16) * 8 + quad * 2);
        u64 v0 = gld64(&X1[base]), v1 = gld64(&X1[base + 1]);
        union { u64 u; float2 f; } a, b;
        a.u = v0; b.u = v1;
        xi[g] = make_float4(a.f.x, a.f.y, b.f.x, b.f.y);
      }
      if (t > 0) {
        const u64* src = &hx[((u64)((t - 1) & 1) * 256) * 16];
        #pragma unroll
        for (int cc = 0; cc < 2; ++cc) {
          int idx = tid * 2 + cc;
          int jp = idx >> 4, bbq = idx & 15;
          int j0 = peer0 + jp * 2;
          u64 v0, v1;
          for (;;) {
            v0 = gld64(&src[j0 * 16 + bbq]);
            v1 = gld64(&src[(j0 + 1) * 16 + bbq]);
            if ((unsigned)v0 == (unsigned)t && (unsigned)v1 == (unsigned)t) break;
          }
          hT[bbq * 136 + (j0 >> 1)] = packh2(pay(v0), pay(v1));
        }
      }
      __syncthreads();

      f32x4 acc[4];
      #pragma unroll
      for (int g = 0; g < 4; ++g) {
        f32x4 a; a[0]=xi[g].x; a[1]=xi[g].y; a[2]=xi[g].z; a[3]=xi[g].w;
        acc[g] = a;
      }
      #pragma unroll
      for (int kk = 0; kk < 8; ++kk) {
        union { uint4 u; f16x8 h; } bv;
        bv.u = *(const uint4*)&hT[b16 * 136 + kk * 16 + quad * 4];
        #pragma unroll
        for (int g = 0; g < 4; ++g)
          acc[g] = __builtin_amdgcn_mfma_f32_16x16x32_f16(wf[g][kk], bv.h, acc[g], 0, 0, 0);
      }
      __syncthreads();

      float hv[4];
      #pragma unroll
      for (int r = 0; r < 4; ++r) {
        float cn = fmaf(sigm(acc[1][r]), cst[r], sigm(acc[0][r]) * tanh_f(acc[2][r]));
        hv[r] = sigm(acc[3][r]) * tanh_f(cn);
        cst[r] = cn;
      }
      int j0 = jb * 16 + quad * 4;
      *(float4*)&hsB[(b16 * 192 + t) * 256 + j0] = make_float4(hv[0], hv[1], hv[2], hv[3]);
      hT[b16 * 136 + (j0 >> 1)]     = packh2(hv[0], hv[1]);
      hT[b16 * 136 + (j0 >> 1) + 1] = packh2(hv[2], hv[3]);
      u64* dst = &hx[((u64)(t & 1) * 256) * 16];
      #pragma unroll
      for (int r = 0; r < 4; ++r)
        gst64(&dst[(j0 + r) * 16 + b16], mk64(hv[r], (unsigned)(t + 1)));
    }
    return;
  }

  // --------------- proj: idx -> (bx, ty); 8 timesteps per WG ----------------
  const int idx = bid - 1 - (bid > 8 ? 1 : 0);
  const int bx = idx % 72, ty = idx / 72;
  float* As  = smem;              // [16][258]
  float* Wsh = smem + 16 * 258;   // [256][34]
  unsigned* cnt = (unsigned*)(ws + OFF_CN);

  const float* W; const float* bias; int ldw, woff, c0, mode; float* out;
  if (bx < 32)      { W = W_ih; bias = b_l;  ldw = 256; woff = 0;   c0 = bx * 32;        mode = 0; out = ws + OFF_X1F; }
  else if (bx < 64) { W = Wc;   bias = bc;   ldw = 768; woff = 0;   c0 = (bx - 32) * 32; mode = 1; out = ws + OFF_XPRE; }
  else              { W = Ws_w; bias = Ws_b; ldw = 768; woff = 512; c0 = (bx - 64) * 32; mode = 2; out = ws + OFF_XB3; }

  for (int i = tid; i < 8192; i += 512) {
    int c = i >> 8, k = i & 255;
    Wsh[k * 34 + c] = W[(c0 + c) * ldw + woff + k];
  }
  const int r = tid >> 5, c = tid & 31;
  const int cg = c0 + c;
  const float bv = bias[cg];

  for (int tt = 0; tt < 8; ++tt) {
    int t = ty * 8 + tt;
    __syncthreads();
    for (int i = tid; i < 4096; i += 512) {
      int rr = i >> 8, k = i & 255;
      As[rr * 258 + k] = x[(t * 16 + rr) * 256 + k];
    }
    __syncthreads();
    float acc = bv;
    for (int k = 0; k < 256; k += 2) {
      float2 a = *(const float2*)&As[r * 258 + k];
      acc = fmaf(a.x, Wsh[k * 34 + c], acc);
      acc = fmaf(a.y, Wsh[(k + 1) * 34 + c], acc);
    }
    if (mode == 0) {
      gstf(&out[((t * 64 + (cg >> 4)) * 16 + r) * 16 + (cg & 15)], acc);
      __syncthreads();
      if (tid == 0)
        __hip_atomic_fetch_add(&cnt[t], 1u, __ATOMIC_RELAXED, __HIP_MEMORY_SCOPE_AGENT);
    } else if (mode == 1) {
      out[(t * 16 + r) * 1024 + cg] = acc;
    } else {
      out[(t * 16 + r) * 256 + cg] = acc;
    }
  }
}

// ===================== task: 128 WGs x 512 thr; 2 polls/step =================
// b = bid&15 (co-XCD domain), s = bid>>4 owns h-cols [32s,32s+32), pre-cols
// {g*256+32s+jl}, and tp-slice [24s,24s+24) for scores.
__global__ __launch_bounds__(512, 2) void task_kernel(
    const float* __restrict__ xb3, const float* __restrict__ xpre,
    const float* __restrict__ hsB, const float* __restrict__ Us_w,
    const float* __restrict__ Us_b, const float* __restrict__ Wc,
    const float* __restrict__ Ws_w,
    u64* __restrict__ Hbuf, u64* __restrict__ HPbuf, u64* __restrict__ Ebuf,
    float* __restrict__ out){
  extern __shared__ char smem[];
  unsigned* WCH  = (unsigned*)(smem + L_WCH);
  unsigned* G    = (unsigned*)(smem + L_G);
  unsigned* WS2  = (unsigned*)(smem + L_WS2);
  unsigned* BS   = (unsigned*)(smem + L_BASES);
  float* HT2     = (float*)(smem + L_HT2);
  unsigned* H2L  = (unsigned*)(smem + L_H2L);
  float* EL      = (float*)(smem + L_EL);
  unsigned* EH2  = (unsigned*)(smem + L_EH2);
  float* PREL    = (float*)(smem + L_PREL);
  unsigned* HN2  = (unsigned*)(smem + L_HN2);
  float* MSC     = (float*)(smem + L_MSC);
  float* HL      = (float*)(smem + L_HL);
  float* XPL     = (float*)(smem + L_XPL);
  float* HNL     = (float*)(smem + L_HNL);
  float* USL     = (float*)(smem + L_USL);
  unsigned* HSL  = (unsigned*)(smem + L_HSL);
  unsigned* CHK  = (unsigned*)(smem + L_CHUNK);
  float* BF      = (float*)(smem + L_BF32);

  const int tid = threadIdx.x;
  const int bb = blockIdx.x & 15;
  const int s  = blockIdx.x >> 4;
  const int wave = tid >> 6, lane = tid & 63;
  const int m16 = lane & 15, quad = lane >> 4;

  // ---- P1: hs (f16) full 192 rows ----
  for (int i = tid; i < 24576; i += 512) {
    int tp = i >> 7, k2 = i & 127;
    const float* hp = &hsB[(bb * 192 + tp) * 256 + 2 * k2];
    HSL[tp * 128 + k2] = packh2(hp[0], hp[1]);
  }
  __syncthreads();

  // ---- P3: base = xb3 + hs @ Ws1^T (own 24 tp x 256 c), MFMA ----
  for (int cc = 0; cc < 8; ++cc) {
    for (int i = tid; i < 4096; i += 512) {
      int cl = i >> 7, k2 = i & 127;
      const float* wp = &Ws_w[(cc * 32 + cl) * 768 + 2 * k2];
      CHK[cl * 128 + k2] = packh2(wp[0], wp[1]);
    }
    __syncthreads();
    if (wave < 4) {
      int tt = wave & 1, lt = wave >> 1;
      int col = cc * 32 + lt * 16 + m16;
      f32x4 a;
      #pragma unroll
      for (int rr = 0; rr < 4; ++rr)
        a[rr] = xb3[((24 * s + tt * 8 + quad * 4 + rr) * 16 + bb) * 256 + col];
      #pragma unroll
      for (int kk = 0; kk < 8; ++kk) {
        union { uint4 u; f16x8 h; } av, bv;
        av.u = *(const uint4*)&HSL[(24 * s + tt * 8 + m16) * 128 + kk * 16 + quad * 4];
        bv.u = *(const uint4*)&CHK[(lt * 16 + m16) * 128 + kk * 16 + quad * 4];
        a = __builtin_amdgcn_mfma_f32_16x16x32_f16(av.h, bv.h, a, 0, 0, 0);
      }
      #pragma unroll
      for (int rr = 0; rr < 4; ++rr) {
        int tpl = tt * 8 + quad * 4 + rr;
        if (tt == 0 || tpl >= 16) BF[tpl * 257 + col] = a[rr];
      }
    }
    __syncthreads();
  }
  // ---- P4: repack base f32 -> f16 (read-all, barrier, write) ----
  {
    float pa[6], pb[6];
    #pragma unroll
    for (int ii = 0; ii < 6; ++ii) {
      int i = tid + ii * 512;
      int tp = i >> 7, c2 = i & 127;
      pa[ii] = BF[tp * 257 + 2 * c2];
      pb[ii] = BF[tp * 257 + 2 * c2 + 1];
    }
    __syncthreads();
    #pragma unroll
    for (int ii = 0; ii < 6; ++ii) {
      int i = tid + ii * 512;
      int tp = i >> 7, c2 = i & 127;
      BS[tp * 129 + c2] = packh2(pa[ii], pb[ii]);
    }
  }
  __syncthreads();

  // ---- P5: G = hs @ Wc_R^T slice (192 tp x own 128 l), MFMA, G in regs ----
  f32x4 gacc[16];
  for (int lc = 0; lc < 4; ++lc) {
    for (int i = tid; i < 4096; i += 512) {
      int ll = i >> 7, k2 = i & 127;
      const float* wp = &Wc[(lc * 256 + 32 * s + ll) * 768 + 256 + 2 * k2];
      CHK[ll * 128 + k2] = packh2(wp[0], wp[1]);
    }
    __syncthreads();
    #pragma unroll
    for (int ts = 0; ts < 2; ++ts) {
      int tt = wave + ts * 8;
      if (tt < 12) {
        #pragma unroll
        for (int lt = 0; lt < 2; ++lt) {
          f32x4 a; a[0]=0.f; a[1]=0.f; a[2]=0.f; a[3]=0.f;
          #pragma unroll
          for (int kk = 0; kk < 8; ++kk) {
            union { uint4 u; f16x8 h; } av, bv;
            av.u = *(const uint4*)&HSL[(tt * 16 + m16) * 128 + kk * 16 + quad * 4];
            bv.u = *(const uint4*)&CHK[(lt * 16 + m16) * 128 + kk * 16 + quad * 4];
            a = __builtin_amdgcn_mfma_f32_16x16x32_f16(av.h, bv.h, a, 0, 0, 0);
          }
          gacc[lc * 4 + ts * 2 + lt] = a;
        }
      }
    }
    __syncthreads();
  }
  // ---- P6: write G f16 (pairs over tp) ; P7: fill Wch, Ws2s, usl ----
  #pragma unroll
  for (int lc = 0; lc < 4; ++lc) {
    #pragma unroll
    for (int ts = 0; ts < 2; ++ts) {
      int tt = wave + ts * 8;
      if (tt < 12) {
        #pragma unroll
        for (int lt = 0; lt < 2; ++lt) {
          f32x4 a = gacc[lc * 4 + ts * 2 + lt];
          int l = lc * 32 + lt * 16 + m16;
          int tp2 = tt * 8 + quad * 2;
          G[l * 100 + tp2]     = packh2(a[0], a[1]);
          G[l * 100 + tp2 + 1] = packh2(a[2], a[3]);
        }
      }
    }
  }
  for (int i = tid; i < 16384; i += 512) {
    int l = i >> 7, k2 = i & 127;
    int row = (l >> 5) * 256 + 32 * s + (l & 31);
    const float* wp = &Wc[row * 768 + 512 + 2 * k2];
    WCH[l * 132 + k2] = packh2(wp[0], wp[1]);
  }
  for (int i = tid; i < 4096; i += 512) {
    int cI = i >> 4, k2 = i & 15;
    const float* wp = &Ws_w[cI * 768 + 256 + 32 * s + 2 * k2];
    WS2[cI * 17 + k2] = packh2(wp[0], wp[1]);
  }
  if (tid < 256) USL[tid] = Us_w[tid];
  const float usb = Us_b[0];
  __syncthreads();

  u64* Hb = Hbuf + bb * 256;
  u64* HP = HPbuf + bb * 2048;
  u64* Eb = Ebuf + bb * 192;
  const uint4* Gp   = (const uint4*)G;
  const uint4* Wp   = (const uint4*)WCH;
  const uint4* H2p  = (const uint4*)H2L;
  const uint4* E2p  = (const uint4*)EH2;
  float creg = 0.f;

  const int l5 = tid >> 2, q5 = tid & 3;        // S5 roles
  const int cS1 = tid & 255, shS1 = tid >> 8;   // S1 roles

  for (int t = 0; t < T_LEN; ++t) {
    const unsigned tg = (unsigned)t;

    // prefetch xpre -> LDS (consumed at S5, after 4 barriers)
    if (tid < 128)
      XPL[tid] = xpre[(t * 16 + bb) * 1024 + (tid >> 5) * 256 + 32 * s + (tid & 31)];

    // ---- S1: poll h + hterm partials (published end of prev step) ----
    {
      const u64* hpp = &HP[shS1 * 256 + cS1];
      u64 v0, v1, v2, v3, vh = 0;
      for (;;) {
        v0 = gld64(hpp); v1 = gld64(hpp + 512);
        v2 = gld64(hpp + 1024); v3 = gld64(hpp + 1536);
        bool ok = ((unsigned)v0 == tg) & ((unsigned)v1 == tg) &
                  ((unsigned)v2 == tg) & ((unsigned)v3 == tg);
        if (tid < 256) { vh = gld64(&Hb[tid]); ok &= ((unsigned)vh == tg); }
        if (ok) break;
      }
      HT2[shS1 * 256 + cS1] = pay(v0) + pay(v1) + pay(v2) + pay(v3);
      if (tid < 256) HL[tid] = pay(vh);
    }
    __syncthreads();  // B1
    if (tid < 256) HT2[tid] = HT2[tid] + HT2[256 + tid];
    if (tid < 128) H2L[tid] = packh2(HL[2 * tid], HL[2 * tid + 1]);
    __syncthreads();  // B2

    // ---- S3: scores, own 24 tp (wave -> 3 tp, full 256-c reduce) ----
    {
      float4 h4 = *(const float4*)&HT2[lane * 4];
      float4 u4 = *(const float4*)&USL[lane * 4];
      float p[3];
      #pragma unroll
      for (int j = 0; j < 3; ++j) {
        int tpl = wave * 3 + j;
        unsigned b0 = BS[tpl * 129 + lane * 2];
        unsigned b1 = BS[tpl * 129 + lane * 2 + 1];
        float2 f0 = unp2(b0), f1 = unp2(b1);
        p[j] = u4.x * tanh_f(f0.x + h4.x) + u4.y * tanh_f(f0.y + h4.y)
             + u4.z * tanh_f(f1.x + h4.z) + u4.w * tanh_f(f1.y + h4.w);
      }
      #pragma unroll
      for (int off = 32; off >= 1; off >>= 1) {
        p[0] += __shfl_xor(p[0], off);
        p[1] += __shfl_xor(p[1], off);
        p[2] += __shfl_xor(p[2], off);
      }
      if (lane == 0) {
        #pragma unroll
        for (int j = 0; j < 3; ++j) {
          int tpg = 24 * s + wave * 3 + j;
          float e = __expf(p[j] + usb);
          EL[tpg] = e;
          gst64(&Eb[tpg], mk64(e, tg + 1));
        }
      }
    }
    // ---- S4: poll foreign e ----
    if (tid < 192 && (tid < 24 * s || tid >= 24 * s + 24)) {
      u64 v;
      do { v = gld64(&Eb[tid]); } while ((unsigned)v != tg + 1);
      EL[tid] = pay(v);
    }
    __syncthreads();  // B3
    if (tid < 64) {
      float a = EL[tid] + EL[tid + 64] + EL[tid + 128];
      #pragma unroll
      for (int off = 32; off >= 1; off >>= 1) a += __shfl_xor(a, off);
      if (tid == 0) MSC[0] = 1.f / a;
    }
    if (tid < 96) EH2[tid] = packh2(EL[2 * tid], EL[2 * tid + 1]);
    __syncthreads();  // B4

    // ---- S5: pre = xpre + (e.G)/L + Wch.h  (l = tid>>2, K-quarter q) ----
    {
      float pg = 0.f, ph = 0.f;
      #pragma unroll
      for (int i = 0; i < 6; ++i) {
        uint4 gv = Gp[l5 * 25 + q5 * 6 + i];
        uint4 ev = E2p[q5 * 6 + i];
        pg = fdot2(gv.x, ev.x, pg); pg = fdot2(gv.y, ev.y, pg);
        pg = fdot2(gv.z, ev.z, pg); pg = fdot2(gv.w, ev.w, pg);
      }
      #pragma unroll
      for (int i = 0; i < 8; ++i) {
        uint4 wv = Wp[l5 * 33 + q5 * 8 + i];
        uint4 hv = H2p[q5 * 8 + i];
        ph = fdot2(wv.x, hv.x, ph); ph = fdot2(wv.y, hv.y, ph);
        ph = fdot2(wv.z, hv.z, ph); ph = fdot2(wv.w, hv.w, ph);
      }
      float v = pg * MSC[0] + ph;
      v += __shfl_xor(v, 1);
      v += __shfl_xor(v, 2);
      if (q5 == 0) PREL[l5] = v + XPL[l5];
    }
    __syncthreads();  // B5

    // ---- S6: gates + h (tid<32), publish h ----
    if (tid < 32) {
      int jl = tid;
      float pi = PREL[jl], pf = PREL[32 + jl], pg = PREL[64 + jl], po = PREL[96 + jl];
      float cn = fmaf(sigm(pf), creg, sigm(pi) * tanh_f(pg));
      float h = sigm(po) * tanh_f(cn);
      creg = cn;
      HNL[jl] = h;
      out[(bb * 192 + t) * 256 + 32 * s + jl] = h;
      gst64(&Hb[32 * s + jl], mk64(h, tg + 1));
      float hnx = __shfl_down(h, 1);
      if ((jl & 1) == 0) HN2[jl >> 1] = packh2(h, hnx);
    }
    __syncthreads();  // B6

    // ---- S7: hterm partial from own h-slice, publish ----
    if (tid < 256) {
      float a = 0.f;
      #pragma unroll
      for (int i = 0; i < 16; ++i)
        a = fdot2(WS2[tid * 17 + i], HN2[i], a);
      gst64(&HP[s * 256 + tid], mk64(a, tg + 1));
    }
  }
}

extern "C" void kernel_launch(void* const* d_in, const int* in_sizes, int n_in,
                              void* d_out, int out_size, void* d_ws, size_t ws_size,
                              hipStream_t stream) {
  (void)in_sizes; (void)n_in; (void)out_size; (void)ws_size;
  const float* x    = (const float*)d_in[0];
  const float* W_ih = (const float*)d_in[1];
  const float* W_hh = (const float*)d_in[2];
  const float* b_l  = (const float*)d_in[3];
  const float* Ws_w = (const float*)d_in[4];
  const float* Ws_b = (const float*)d_in[5];
  const float* Us_w = (const float*)d_in[6];
  const float* Us_b = (const float*)d_in[7];
  const float* Wc   = (const float*)d_in[8];
  const float* bc   = (const float*)d_in[9];
  float* out = (float*)d_out;
  float* ws = (float*)d_ws;

  hipFuncSetAttribute((const void*)task_kernel,
                      hipFuncAttributeMaxDynamicSharedMemorySize, 160 * 1024);

  // zero exchange region + counters
  initk<<<64, 256, 0, stream>>>(ws + OFF_HX, INIT_WORDS);

  // fused projections (1728 WGs) + shared LSTM (bids 0,8 -> XCD 0)
  fused_pl<<<1730, 512, 0, stream>>>(x, W_ih, b_l, Wc, bc, Ws_w, Ws_b, W_hh, ws);

  // task loop
  task_kernel<<<128, 512, SMEM_TASK, stream>>>(
      ws + OFF_XB3, ws + OFF_XPRE, ws + OFF_HSB, Us_w, Us_b, Wc, Ws_w,
      (u64*)(ws + OFF_HB), (u64*)(ws + OFF_HP), (u64*)(ws + OFF_E), out);
}